// Round 7
// baseline (4178.192 us; speedup 1.0000x reference)
//
#include <hip/hip_runtime.h>

// ---------------------------------------------------------------------------
// MashDecoderV2: 256-layer mamba stack (L=400, D=40) + 65536-query cross-attn
// decoder. f32 throughout (threshold 1.56e-2; current absmax 2e-3).
//
// Stage 1 (round-7): back to the measured-best R4 topology (256 WGs x 320
//   threads, 1 layer/WG, stationary weights in VGPRs, 5 barriers/chunk).
//   R5 (2-stage systolic) and R6 (2-layer sequential) both regressed ~2-3x;
//   topology experiments closed. New: TAGGED HANDOFF - each handoff element
//   is an 8-byte {value, layer_tag} written by ONE relaxed agent-scope 64-bit
//   atomic store. Consumer loads eagerly (no prior flag trip) and validates
//   tags == layer-1; atomicity makes each element self-proving with zero
//   ordering assumptions (R4's racy speculative accept, made safe). Tag miss
//   -> cheap 1-dword flag spin -> guaranteed reload.
// Stage 2: R6 wave-pair query kernel (measured best, ~2x faster than R4's):
//   h = readfirstlane(wave&1) -> weight/k/v addresses wave-uniform.
// ---------------------------------------------------------------------------

#define CH 4
#define NCHUNK 100       // 400 / CH
#define TPB1 320

typedef unsigned long long u64;

__device__ __forceinline__ u64 packvt(float v, unsigned tag) {
  return ((u64)tag << 32) | (u64)__float_as_uint(v);
}
__device__ __forceinline__ float unpv(u64 a) {
  return __uint_as_float((unsigned)a);
}
__device__ __forceinline__ unsigned unpt(u64 a) { return (unsigned)(a >> 32); }

__global__ void init_flags(int* __restrict__ flags) {
  int i = blockIdx.x * 256 + threadIdx.x;
  if (i < 256 * 16) flags[i] = 0;
}

__global__ __launch_bounds__(TPB1, 1) void mamba_pipe(
    const float* __restrict__ mash,
    const float* __restrict__ g_norm_w,   // (256,40)
    const float* __restrict__ g_in_w,     // (256,160,40)
    const float* __restrict__ g_conv_w,   // (256,80,4)
    const float* __restrict__ g_conv_b,   // (256,80)
    const float* __restrict__ g_xp_w,     // (256,35,80)
    const float* __restrict__ g_dt_w,     // (256,80,3)
    const float* __restrict__ g_dt_b,     // (256,80)
    const float* __restrict__ g_alog,     // (256,80,16)
    const float* __restrict__ g_D,        // (256,80)
    const float* __restrict__ g_out_w,    // (256,40,80)
    u64* __restrict__ xb0,
    u64* __restrict__ xb1,
    int* __restrict__ flags)
{
  const int layer = blockIdx.x;
  const int tid = threadIdx.x;

  // activations in LDS (~6 KB)
  __shared__ float xin[160];
  __shared__ float xz[640];
  __shared__ float xs[320];
  __shared__ float dbc[144];        // stride 36
  __shared__ float yb[320];
  __shared__ float xhist[240];      // conv tail

  // ---------------- per-thread stationary weights (registers) --------------
  const int e_in = tid % 160;
  const int tA = tid / 160;
  float w_in_r[40];                 // in_proj row with rmsnorm weight folded
  {
    const float4* g = (const float4*)(g_in_w + layer * 6400 + e_in * 40);
    const float4* nw = (const float4*)(g_norm_w + layer * 40);
#pragma unroll
    for (int k = 0; k < 10; ++k) {
      float4 v = g[k];
      float4 n = nw[k];
      w_in_r[4 * k] = v.x * n.x; w_in_r[4 * k + 1] = v.y * n.y;
      w_in_r[4 * k + 2] = v.z * n.z; w_in_r[4 * k + 3] = v.w * n.w;
    }
  }
  const int d_c = tid % 80;
  const int t_c = tid / 80;
  float cw[4]; float cb;
  {
    float4 v = *(const float4*)(g_conv_w + layer * 320 + d_c * 4);
    cw[0] = v.x; cw[1] = v.y; cw[2] = v.z; cw[3] = v.w;
    cb = g_conv_b[layer * 80 + d_c];
  }
  const int halfp = tid & 1;
  const int p_x = tid >> 1;              // <140 active for x_proj
  const int t_x = p_x / 35, e_x = p_x % 35;
  float w_xp_r[40];
  if (p_x < 140) {
    const float4* g = (const float4*)(g_xp_w + layer * 2800 + e_x * 80 + halfp * 40);
#pragma unroll
    for (int k = 0; k < 10; ++k) {
      float4 v = g[k];
      w_xp_r[4 * k] = v.x; w_xp_r[4 * k + 1] = v.y;
      w_xp_r[4 * k + 2] = v.z; w_xp_r[4 * k + 3] = v.w;
    }
  }
  const int d_ch = tid >> 2;
  const int qq = tid & 3;
  float negA[4], hst[4];
  {
    float4 v = *(const float4*)(g_alog + layer * 1280 + tid * 4);
    negA[0] = -__expf(v.x); negA[1] = -__expf(v.y);
    negA[2] = -__expf(v.z); negA[3] = -__expf(v.w);
    hst[0] = hst[1] = hst[2] = hst[3] = 0.f;
  }
  const float dtw0 = g_dt_w[layer * 240 + d_ch * 3 + 0];
  const float dtw1 = g_dt_w[layer * 240 + d_ch * 3 + 1];
  const float dtw2 = g_dt_w[layer * 240 + d_ch * 3 + 2];
  const float dtb = g_dt_b[layer * 80 + d_ch];
  const float wD = g_D[layer * 80 + d_ch];
  const int p_o = tid >> 1;
  const int t_o = p_o / 40, e_o = p_o % 40;
  float w_out_r[40];
  {
    const float4* g = (const float4*)(g_out_w + layer * 3200 + e_o * 80 + halfp * 40);
#pragma unroll
    for (int k = 0; k < 10; ++k) {
      float4 v = g[k];
      w_out_r[4 * k] = v.x; w_out_r[4 * k + 1] = v.y;
      w_out_r[4 * k + 2] = v.z; w_out_r[4 * k + 3] = v.w;
    }
  }

  for (int i = tid; i < 240; i += TPB1) xhist[i] = 0.f;
  __syncthreads();

  // parity ping-pong; tags disambiguate writers of reused locations
  const u64* srcT = (layer & 1) ? xb0 : xb1;
  u64* dstT = (layer & 1) ? xb1 : xb0;
  int* flag_prev = flags + (layer - 1) * 16;
  int* flag_cur = flags + layer * 16;
  const unsigned exp_tag = (unsigned)(layer - 1);

  for (int c = 0; c < NCHUNK; ++c) {
    const int t0 = c * CH;

    // ---- Phase A: tagged eager acquire + in_proj (rmsnorm folded) ----
    float ss0, sd0, ss1, sd1, xi = 0.f;
    if (layer == 0) {
      const float4* sp0 = (const float4*)(mash + (t0 + tA) * 40);
      const float4* sp1 = (const float4*)(mash + (t0 + tA + 2) * 40);
      ss0 = sd0 = ss1 = sd1 = 0.f;
#pragma unroll
      for (int k = 0; k < 10; ++k) {
        float4 v = sp0[k];
        ss0 += v.x * v.x + v.y * v.y + v.z * v.z + v.w * v.w;
        sd0 += w_in_r[4 * k] * v.x + w_in_r[4 * k + 1] * v.y
             + w_in_r[4 * k + 2] * v.z + w_in_r[4 * k + 3] * v.w;
        float4 u = sp1[k];
        ss1 += u.x * u.x + u.y * u.y + u.z * u.z + u.w * u.w;
        sd1 += w_in_r[4 * k] * u.x + w_in_r[4 * k + 1] * u.y
             + w_in_r[4 * k + 2] * u.z + w_in_r[4 * k + 3] * u.w;
      }
      if (tid < 160) xi = mash[t0 * 40 + tid];
    } else {
      const u64* s0 = srcT + (t0 + tA) * 40;
      const u64* s1 = srcT + (t0 + tA + 2) * 40;
      const u64* sx = srcT + t0 * 40 + tid;
      bool ok = true;
      // eager attempt: one IF$ trip, self-validating via per-element tags
      {
        ss0 = sd0 = ss1 = sd1 = 0.f;
#pragma unroll
        for (int d = 0; d < 40; ++d) {
          u64 a = __hip_atomic_load(s0 + d, __ATOMIC_RELAXED,
                                    __HIP_MEMORY_SCOPE_AGENT);
          u64 b = __hip_atomic_load(s1 + d, __ATOMIC_RELAXED,
                                    __HIP_MEMORY_SCOPE_AGENT);
          float v = unpv(a), u = unpv(b);
          ok &= (unpt(a) == exp_tag) & (unpt(b) == exp_tag);
          ss0 += v * v; sd0 += w_in_r[d] * v;
          ss1 += u * u; sd1 += w_in_r[d] * u;
        }
        if (tid < 160) {
          u64 a = __hip_atomic_load(sx, __ATOMIC_RELAXED,
                                    __HIP_MEMORY_SCOPE_AGENT);
          xi = unpv(a);
          ok &= (unpt(a) == exp_tag);
        }
      }
      if (!__all((int)ok)) {
        // slow path: cheap 1-dword wave-uniform flag spin, then reload
        // (flag set after producer's B5 vmcnt drain -> reload guaranteed)
        while (__hip_atomic_load(flag_prev, __ATOMIC_RELAXED,
                                 __HIP_MEMORY_SCOPE_AGENT) <= c)
          __builtin_amdgcn_s_sleep(1);
        ss0 = sd0 = ss1 = sd1 = 0.f;
#pragma unroll
        for (int d = 0; d < 40; ++d) {
          float v = unpv(__hip_atomic_load(s0 + d, __ATOMIC_RELAXED,
                                           __HIP_MEMORY_SCOPE_AGENT));
          float u = unpv(__hip_atomic_load(s1 + d, __ATOMIC_RELAXED,
                                           __HIP_MEMORY_SCOPE_AGENT));
          ss0 += v * v; sd0 += w_in_r[d] * v;
          ss1 += u * u; sd1 += w_in_r[d] * u;
        }
        if (tid < 160)
          xi = unpv(__hip_atomic_load(sx, __ATOMIC_RELAXED,
                                      __HIP_MEMORY_SCOPE_AGENT));
      }
    }
    xz[tA * 160 + e_in] = sd0 * rsqrtf(ss0 * (1.f / 40.f) + 1e-5f);
    xz[(tA + 2) * 160 + e_in] = sd1 * rsqrtf(ss1 * (1.f / 40.f) + 1e-5f);
    if (tid < 160) xin[tid] = xi;
    __syncthreads();                                   // B1: xz, xin ready

    // ---- causal depthwise conv(4) + silu ----
    {
      float acc = cb;
#pragma unroll
      for (int j = 0; j < 4; ++j) {
        int lt = t_c - 3 + j;
        float xv = (lt >= 0) ? xz[lt * 160 + d_c] : xhist[(lt + 3) * 80 + d_c];
        acc += cw[j] * xv;
      }
      xs[t_c * 80 + d_c] = acc / (1.f + __expf(-acc));
    }
    __syncthreads();                                   // B2: xs ready

    // ---- x_proj: pair half-dots + shfl merge; idle threads refresh xhist ----
    if (p_x < 140) {
      const float4* xp = (const float4*)&xs[t_x * 80 + halfp * 40];
      float s = 0.f;
#pragma unroll
      for (int k = 0; k < 10; ++k) {
        float4 v = xp[k];
        s += w_xp_r[4 * k] * v.x + w_xp_r[4 * k + 1] * v.y
           + w_xp_r[4 * k + 2] * v.z + w_xp_r[4 * k + 3] * v.w;
      }
      s += __shfl_xor(s, 1);
      if (halfp == 0) dbc[t_x * 36 + e_x] = s;
    } else {
      for (int k = tid - 280; k < 240; k += 40)
        xhist[k] = xz[(1 + k / 80) * 160 + (k % 80)];
    }
    __syncthreads();                                   // B3: dbc ready

    // ---- selective scan; dt inline; state in regs ----
#pragma unroll
    for (int t = 0; t < CH; ++t) {
      const float* db = &dbc[t * 36];
      float sdt = dtb + db[0] * dtw0 + db[1] * dtw1 + db[2] * dtw2;
      float dtval = (sdt > 15.f) ? sdt : __logf(1.f + __expf(sdt));
      float xval = xs[t * 80 + d_ch];
      float part = 0.f;
#pragma unroll
      for (int j = 0; j < 4; ++j) {
        int s_i = qq * 4 + j;
        float Bv = db[3 + s_i];
        float Cv = db[19 + s_i];
        hst[j] = __expf(dtval * negA[j]) * hst[j] + dtval * Bv * xval;
        part += hst[j] * Cv;
      }
      part += __shfl_xor(part, 1);
      part += __shfl_xor(part, 2);
      if (qq == 0) {
        float yv = part + xval * wD;
        float z = xz[t * 160 + 80 + d_ch];
        yb[t * 80 + d_ch] = yv * z / (1.f + __expf(-z));
      }
    }
    __syncthreads();                                   // B4: yb ready

    // ---- out_proj + residual -> tagged 8B atomic store ----
    {
      const float4* yp = (const float4*)&yb[t_o * 80 + halfp * 40];
      float s = 0.f;
#pragma unroll
      for (int k = 0; k < 10; ++k) {
        float4 v = yp[k];
        s += w_out_r[4 * k] * v.x + w_out_r[4 * k + 1] * v.y
           + w_out_r[4 * k + 2] * v.z + w_out_r[4 * k + 3] * v.w;
      }
      s += __shfl_xor(s, 1);
      if (halfp == 0)
        __hip_atomic_store(&dstT[t0 * 40 + p_o], packvt(xin[p_o] + s, (unsigned)layer),
                           __ATOMIC_RELAXED, __HIP_MEMORY_SCOPE_AGENT);
    }
    __syncthreads();        // B5: drains vmcnt -> all tagged stores at IF$
    if (tid == 0)
      __hip_atomic_store(flag_cur, c + 1, __ATOMIC_RELAXED,
                         __HIP_MEMORY_SCOPE_AGENT);
  }
}

// ---- context side of cross-attn: cn = LN(x_final), kv = cn @ ca_kv_w^T ----
__global__ __launch_bounds__(64) void kv_kernel(
    const u64* __restrict__ xfinT,       // tagged {value, layer_tag} elements
    const float* __restrict__ lnc_w, const float* __restrict__ lnc_b,
    const float* __restrict__ kv_w,
    float* __restrict__ kbuf, float* __restrict__ vbuf)
{
  int t = blockIdx.x;
  int lane = threadIdx.x;
  float x = (lane < 40) ? unpv(xfinT[t * 40 + lane]) : 0.f;
  float s = x;
#pragma unroll
  for (int o = 32; o >= 1; o >>= 1) s += __shfl_xor(s, o);
  float m = s * (1.f / 40.f);
  float dv = (lane < 40) ? (x - m) : 0.f;
  float v2 = dv * dv;
#pragma unroll
  for (int o = 32; o >= 1; o >>= 1) v2 += __shfl_xor(v2, o);
  float rstd = rsqrtf(v2 * (1.f / 40.f) + 1e-5f);
  __shared__ float cn[40];
  if (lane < 40) cn[lane] = dv * rstd * lnc_w[lane] + lnc_b[lane];
  __syncthreads();
  for (int e = lane; e < 80; e += 64) {
    float acc = 0.f;
#pragma unroll
    for (int d = 0; d < 40; ++d) acc += cn[d] * kv_w[e * 40 + d];
    if (e < 40) kbuf[t * 40 + e] = acc;
    else vbuf[t * 40 + (e - 40)] = acc;
  }
}

// ---- per-query decode: wave-pair split; all weight/k/v addresses uniform ----
__global__ __launch_bounds__(256) void query_kernel(
    const float* __restrict__ qry,
    const float* __restrict__ pe_w, const float* __restrict__ pe_b,
    const float* __restrict__ lnq_w, const float* __restrict__ lnq_b,
    const float* __restrict__ qw,
    const float* __restrict__ ow, const float* __restrict__ ob,
    const float* __restrict__ flw, const float* __restrict__ flb,
    const float* __restrict__ w1, const float* __restrict__ b1,
    const float* __restrict__ w2, const float* __restrict__ b2,
    const float* __restrict__ outw, const float* __restrict__ outb,
    const float* __restrict__ kbuf, const float* __restrict__ vbuf,
    float* __restrict__ out)
{
  const int tid = threadIdx.x;
  const int h = __builtin_amdgcn_readfirstlane((tid >> 6) & 1);  // wave in pair
  const int pj = tid >> 7;               // wave-pair 0/1
  const int lane = tid & 63;
  const int n = blockIdx.x * 128 + pj * 64 + lane;   // query id
  const int ptn = tid ^ 64;              // partner thread (other wave in pair)
  __shared__ float colbuf[40 * 256];
  __shared__ float redm[256], redl[256];

  const float qx = qry[n * 3 + 0], qy = qry[n * 3 + 1], qz = qry[n * 3 + 2];

  // ---- PE-MLP, octaves split by wave half ----
  float qp[40];
#pragma unroll
  for (int d = 0; d < 40; ++d) qp[d] = 0.f;
#pragma unroll
  for (int jj = 0; jj < 4; ++jj) {
    const int j = h * 4 + jj;
    float f = 3.14159265358979323846f * (float)(1 << j);
    float sx, cx, sy, cy, sz, cz;
    __sincosf(qx * f, &sx, &cx);
    __sincosf(qy * f, &sy, &cy);
    __sincosf(qz * f, &sz, &cz);
#pragma unroll
    for (int d = 0; d < 40; ++d) {
      const float* r = pe_w + d * 51;
      qp[d] += sx * r[j] + sy * r[j + 8] + sz * r[j + 16]
             + cx * r[j + 24] + cy * r[j + 32] + cz * r[j + 40];
    }
  }
#pragma unroll
  for (int d = 0; d < 40; ++d) colbuf[d * 256 + tid] = qp[d];
  __syncthreads();                                    // B1
  float qe[40];
#pragma unroll
  for (int d = 0; d < 40; ++d) {
    const float* r = pe_w + d * 51;
    qe[d] = pe_b[d] + qp[d] + colbuf[d * 256 + ptn]
          + qx * r[48] + qy * r[49] + qz * r[50];
  }
  __syncthreads();                                    // B2 (colbuf free)

  // ---- LN(qe) -> qn regs; q-proj split by d-half ----
  float qn[40];
  {
    float m = 0.f;
#pragma unroll
    for (int d = 0; d < 40; ++d) m += qe[d];
    m *= (1.f / 40.f);
    float var = 0.f;
#pragma unroll
    for (int d = 0; d < 40; ++d) { float dv = qe[d] - m; var += dv * dv; }
    float rstd = rsqrtf(var * (1.f / 40.f) + 1e-5f);
#pragma unroll
    for (int d = 0; d < 40; ++d) qn[d] = (qe[d] - m) * rstd * lnq_w[d] + lnq_b[d];
  }
  float qnh[20];
#pragma unroll
  for (int dd = 0; dd < 20; ++dd) qnh[dd] = h ? qn[dd + 20] : qn[dd];
  float q[40];
#pragma unroll
  for (int e = 0; e < 40; ++e) q[e] = 0.f;
#pragma unroll 1
  for (int dd = 0; dd < 20; ++dd) {
    const float qv = qnh[dd];
    const int d = h * 20 + dd;
#pragma unroll
    for (int e = 0; e < 40; ++e) q[e] += qv * qw[e * 40 + d];
  }
#pragma unroll
  for (int e = 0; e < 40; ++e) colbuf[e * 256 + tid] = q[e];
  __syncthreads();                                    // B3
#pragma unroll
  for (int e = 0; e < 40; ++e) q[e] += colbuf[e * 256 + ptn];
  __syncthreads();                                    // B4 (colbuf free)

  // ---- flash attention over this wave's 200 tokens (uniform addresses) ----
  float acc[40];
#pragma unroll
  for (int d = 0; d < 40; ++d) acc[d] = 0.f;
  float mx = -1e30f, l = 0.f;
  const float scale = 0.15811388300841897f;  // 40^-0.5
  const int tbeg = h * 200, tend = tbeg + 200;
#pragma unroll 1
  for (int t = tbeg; t < tend; ++t) {
    const float4* kr = (const float4*)(kbuf + t * 40);
    float s0 = 0.f, s1 = 0.f, s2 = 0.f, s3 = 0.f;
#pragma unroll
    for (int k = 0; k < 10; ++k) {
      float4 k4 = kr[k];
      s0 += q[4 * k] * k4.x; s1 += q[4 * k + 1] * k4.y;
      s2 += q[4 * k + 2] * k4.z; s3 += q[4 * k + 3] * k4.w;
    }
    float s = ((s0 + s1) + (s2 + s3)) * scale;
    if (s > mx) {
      float corr = __expf(mx - s);
      l *= corr;
#pragma unroll
      for (int d = 0; d < 40; ++d) acc[d] *= corr;
      mx = s;
    }
    float p = __expf(s - mx);
    l += p;
    const float4* vr = (const float4*)(vbuf + t * 40);
#pragma unroll
    for (int k = 0; k < 10; ++k) {
      float4 v4 = vr[k];
      acc[4 * k] += p * v4.x; acc[4 * k + 1] += p * v4.y;
      acc[4 * k + 2] += p * v4.z; acc[4 * k + 3] += p * v4.w;
    }
  }
  // merge across the wave pair via LDS (symmetric)
#pragma unroll
  for (int d = 0; d < 40; ++d) colbuf[d * 256 + tid] = acc[d];
  redm[tid] = mx; redl[tid] = l;
  __syncthreads();                                    // B5
  float lat[40];
  {
    float m2 = redm[ptn];
    float l2 = redl[ptn];
    float nm = fmaxf(mx, m2);
    float a = __expf(mx - nm), b = __expf(m2 - nm);
    float lm = l * a + l2 * b;
    float linv = 1.f / lm;
#pragma unroll
    for (int d = 0; d < 40; ++d)
      lat[d] = (acc[d] * a + colbuf[d * 256 + ptn] * b) * linv;
  }
  __syncthreads();                                    // B6 (colbuf free)

  // ---- lat2 = lat @ ca_out_w^T + ob, split by d-half ----
  float lath[20];
#pragma unroll
  for (int dd = 0; dd < 20; ++dd) lath[dd] = h ? lat[dd + 20] : lat[dd];
  float lp[40];
#pragma unroll
  for (int e = 0; e < 40; ++e) lp[e] = 0.f;
#pragma unroll 1
  for (int dd = 0; dd < 20; ++dd) {
    const float lv = lath[dd];
    const int d = h * 20 + dd;
#pragma unroll
    for (int e = 0; e < 40; ++e) lp[e] += lv * ow[e * 40 + d];
  }
#pragma unroll
  for (int e = 0; e < 40; ++e) colbuf[e * 256 + tid] = lp[e];
  __syncthreads();                                    // B7
  float lat2[40];
#pragma unroll
  for (int e = 0; e < 40; ++e) lat2[e] = ob[e] + lp[e] + colbuf[e * 256 + ptn];
  __syncthreads();                                    // B8 (colbuf free)

  // ---- LN + FFN (e-range split by wave half) ----
  float hh[40];
  {
    float m = 0.f;
#pragma unroll
    for (int d = 0; d < 40; ++d) m += lat2[d];
    m *= (1.f / 40.f);
    float var = 0.f;
#pragma unroll
    for (int d = 0; d < 40; ++d) { float dv = lat2[d] - m; var += dv * dv; }
    float rstd = rsqrtf(var * (1.f / 40.f) + 1e-5f);
#pragma unroll
    for (int d = 0; d < 40; ++d) hh[d] = (lat2[d] - m) * rstd * flw[d] + flb[d];
  }
  float ff[40];
#pragma unroll
  for (int d = 0; d < 40; ++d) ff[d] = 0.f;
#pragma unroll 1
  for (int ee = 0; ee < 80; ++ee) {
    const int e = h * 80 + ee;
    const float* r1 = w1 + e * 40;
    const float* r2 = w1 + (160 + e) * 40;
    float a0 = 0.f, a1 = 0.f;
#pragma unroll
    for (int d = 0; d < 40; ++d) { a0 += hh[d] * r1[d]; a1 += hh[d] * r2[d]; }
    float x1 = a0 + b1[e];
    float g = a1 + b1[160 + e];
    float tv = x1 * (0.5f * g * (1.f + erff(g * 0.70710678118654752f)));
#pragma unroll
    for (int d = 0; d < 40; ++d) ff[d] += tv * w2[d * 160 + e];
  }
#pragma unroll
  for (int d = 0; d < 40; ++d) colbuf[d * 256 + tid] = ff[d];
  __syncthreads();                                    // B9
  float r = outb[0];
#pragma unroll
  for (int d = 0; d < 40; ++d) {
    float f = ff[d] + colbuf[d * 256 + ptn] + b2[d];
    r += (lat2[d] + f) * outw[d];
  }
  if (h == 0) out[n] = r;
}

extern "C" void kernel_launch(void* const* d_in, const int* in_sizes, int n_in,
                              void* d_out, int out_size, void* d_ws, size_t ws_size,
                              hipStream_t stream) {
  const float* mash   = (const float*)d_in[0];
  const float* qry    = (const float*)d_in[1];
  const float* lnw    = (const float*)d_in[2];
  const float* linw   = (const float*)d_in[3];
  const float* lconvw = (const float*)d_in[4];
  const float* lconvb = (const float*)d_in[5];
  const float* lxpw   = (const float*)d_in[6];
  const float* ldtw   = (const float*)d_in[7];
  const float* ldtb   = (const float*)d_in[8];
  const float* lAlog  = (const float*)d_in[9];
  const float* lD     = (const float*)d_in[10];
  const float* loutw  = (const float*)d_in[11];
  const float* pew    = (const float*)d_in[12];
  const float* peb    = (const float*)d_in[13];
  const float* lnqw   = (const float*)d_in[14];
  const float* lnqb   = (const float*)d_in[15];
  const float* lncw   = (const float*)d_in[16];
  const float* lncb   = (const float*)d_in[17];
  const float* qw     = (const float*)d_in[18];
  const float* kvw    = (const float*)d_in[19];
  const float* oww    = (const float*)d_in[20];
  const float* owb    = (const float*)d_in[21];
  const float* flnw   = (const float*)d_in[22];
  const float* flnb   = (const float*)d_in[23];
  const float* w1     = (const float*)d_in[24];
  const float* b1     = (const float*)d_in[25];
  const float* w2     = (const float*)d_in[26];
  const float* b2     = (const float*)d_in[27];
  const float* outw   = (const float*)d_in[28];
  const float* outb   = (const float*)d_in[29];

  // ws layout: xb0t[16000 u64] xb1t[16000 u64] kbuf[16000 f] vbuf[16000 f]
  //            flags[256*16 int]   (~450 KB total)
  u64* xb0t = (u64*)d_ws;
  u64* xb1t = xb0t + 16000;
  float* kbuf = (float*)(xb1t + 16000);
  float* vbuf = kbuf + 16000;
  int* flags = (int*)(vbuf + 16000);

  hipLaunchKernelGGL(init_flags, dim3(16), dim3(256), 0, stream, flags);
  hipLaunchKernelGGL(mamba_pipe, dim3(256), dim3(TPB1), 0, stream,
                     mash, lnw, linw, lconvw, lconvb, lxpw, ldtw, ldtb, lAlog,
                     lD, loutw, xb0t, xb1t, flags);
  // layer 255 (odd) writes xb1t
  hipLaunchKernelGGL(kv_kernel, dim3(400), dim3(64), 0, stream,
                     xb1t, lncw, lncb, kvw, kbuf, vbuf);
  hipLaunchKernelGGL(query_kernel, dim3(512), dim3(256), 0, stream,
                     qry, pew, peb, lnqw, lnqb, qw, oww, owb, flnw, flnb,
                     w1, b1, w2, b2, outw, outb, kbuf, vbuf, (float*)d_out);
}

// Round 8
// 2167.873 us; speedup vs baseline: 1.9273x; 1.9273x over previous
//
#include <hip/hip_runtime.h>

// ---------------------------------------------------------------------------
// MashDecoderV2: 256-layer mamba stack (L=400, D=40) + 65536-query cross-attn
// decoder. f32 throughout (threshold 1.56e-2; current absmax 2e-3).
//
// Round-8 = composition of the two measured-best components:
// Stage 1: R4 topology (best: 1745us). 256 WGs x 320 threads, 1 layer/WG,
//   stationary weights in VGPRs, 5 barriers/chunk, rmsnorm folded into
//   in_proj. Handoff = ORDERED protocol (safe): every wave polls the
//   producer's flag (relaxed agent atomic), then issues its data loads in
//   program order after the observed flag -> fresh at IF$ (producer drained
//   via B5 before flag store). Data moves as 8B dwordx2 atomics (halves
//   acquire/drain VMEM ops vs R4). No speculation (R4's race removed; R7's
//   eager-tag variant paid 2 round trips/crossing and regressed).
// Stage 2: R6 wave-pair query kernel (measured best, ~2x over lane-pair):
//   h = readfirstlane(wave&1) -> all weight/k/v addresses wave-uniform
//   (scalar path); pair merges via LDS columns.
// ---------------------------------------------------------------------------

#define CH 4
#define NCHUNK 100       // 400 / CH
#define TPB1 320

typedef unsigned long long u64;

__device__ __forceinline__ u64 pack2(float a, float b) {
  return ((u64)__float_as_uint(b) << 32) | (u64)__float_as_uint(a);
}
__device__ __forceinline__ float unplo(u64 a) {
  return __uint_as_float((unsigned)a);
}
__device__ __forceinline__ float unphi(u64 a) {
  return __uint_as_float((unsigned)(a >> 32));
}

__global__ void init_flags(int* __restrict__ flags) {
  int i = blockIdx.x * 256 + threadIdx.x;
  if (i < 256 * 16) flags[i] = 0;
}

__global__ __launch_bounds__(TPB1) void mamba_pipe(
    const float* __restrict__ mash,
    const float* __restrict__ g_norm_w,   // (256,40)
    const float* __restrict__ g_in_w,     // (256,160,40)
    const float* __restrict__ g_conv_w,   // (256,80,4)
    const float* __restrict__ g_conv_b,   // (256,80)
    const float* __restrict__ g_xp_w,     // (256,35,80)
    const float* __restrict__ g_dt_w,     // (256,80,3)
    const float* __restrict__ g_dt_b,     // (256,80)
    const float* __restrict__ g_alog,     // (256,80,16)
    const float* __restrict__ g_D,        // (256,80)
    const float* __restrict__ g_out_w,    // (256,40,80)
    float* __restrict__ xb0,
    float* __restrict__ xb1,
    int* __restrict__ flags)
{
  const int layer = blockIdx.x;
  const int tid = threadIdx.x;

  // activations in LDS (~6 KB)
  __shared__ float xin[160];
  __shared__ float xz[640];
  __shared__ float xs[320];
  __shared__ float dbc[144];        // stride 36
  __shared__ float yb[320];
  __shared__ float xhist[240];      // conv tail

  // ---------------- per-thread stationary weights (registers) --------------
  const int e_in = tid % 160;
  const int tA = tid / 160;
  float w_in_r[40];                 // in_proj row with rmsnorm weight folded
  {
    const float4* g = (const float4*)(g_in_w + layer * 6400 + e_in * 40);
    const float4* nw = (const float4*)(g_norm_w + layer * 40);
#pragma unroll
    for (int k = 0; k < 10; ++k) {
      float4 v = g[k];
      float4 n = nw[k];
      w_in_r[4 * k] = v.x * n.x; w_in_r[4 * k + 1] = v.y * n.y;
      w_in_r[4 * k + 2] = v.z * n.z; w_in_r[4 * k + 3] = v.w * n.w;
    }
  }
  const int d_c = tid % 80;
  const int t_c = tid / 80;
  float cw[4]; float cb;
  {
    float4 v = *(const float4*)(g_conv_w + layer * 320 + d_c * 4);
    cw[0] = v.x; cw[1] = v.y; cw[2] = v.z; cw[3] = v.w;
    cb = g_conv_b[layer * 80 + d_c];
  }
  const int halfp = tid & 1;
  const int p_x = tid >> 1;              // <140 active for x_proj
  const int t_x = p_x / 35, e_x = p_x % 35;
  float w_xp_r[40];
  if (p_x < 140) {
    const float4* g = (const float4*)(g_xp_w + layer * 2800 + e_x * 80 + halfp * 40);
#pragma unroll
    for (int k = 0; k < 10; ++k) {
      float4 v = g[k];
      w_xp_r[4 * k] = v.x; w_xp_r[4 * k + 1] = v.y;
      w_xp_r[4 * k + 2] = v.z; w_xp_r[4 * k + 3] = v.w;
    }
  }
  const int d_ch = tid >> 2;
  const int qq = tid & 3;
  float negA[4], hst[4];
  {
    float4 v = *(const float4*)(g_alog + layer * 1280 + tid * 4);
    negA[0] = -__expf(v.x); negA[1] = -__expf(v.y);
    negA[2] = -__expf(v.z); negA[3] = -__expf(v.w);
    hst[0] = hst[1] = hst[2] = hst[3] = 0.f;
  }
  const float dtw0 = g_dt_w[layer * 240 + d_ch * 3 + 0];
  const float dtw1 = g_dt_w[layer * 240 + d_ch * 3 + 1];
  const float dtw2 = g_dt_w[layer * 240 + d_ch * 3 + 2];
  const float dtb = g_dt_b[layer * 80 + d_ch];
  const float wD = g_D[layer * 80 + d_ch];
  const int p_o = tid >> 1;
  const int t_o = p_o / 40, e_o = p_o % 40;
  float w_out_r[40];
  {
    const float4* g = (const float4*)(g_out_w + layer * 3200 + e_o * 80 + halfp * 40);
#pragma unroll
    for (int k = 0; k < 10; ++k) {
      float4 v = g[k];
      w_out_r[4 * k] = v.x; w_out_r[4 * k + 1] = v.y;
      w_out_r[4 * k + 2] = v.z; w_out_r[4 * k + 3] = v.w;
    }
  }

  for (int i = tid; i < 240; i += TPB1) xhist[i] = 0.f;
  __syncthreads();

  const float* src = (layer == 0) ? mash : ((layer & 1) ? xb0 : xb1);
  float* dst = (layer & 1) ? xb1 : xb0;
  int* flag_prev = flags + (layer - 1) * 16;
  int* flag_cur = flags + layer * 16;

  for (int c = 0; c < NCHUNK; ++c) {
    const int t0 = c * CH;

    // ---- Phase A: ordered acquire + in_proj (rmsnorm folded) ----
    if (layer == 0) {
#pragma unroll
      for (int tt = 0; tt < 2; ++tt) {
        const int t = tA + 2 * tt;
        const float4* sp = (const float4*)(src + (t0 + t) * 40);
        float ss = 0.f, sd = 0.f;
#pragma unroll
        for (int k = 0; k < 10; ++k) {
          float4 v = sp[k];
          ss += v.x * v.x + v.y * v.y + v.z * v.z + v.w * v.w;
          sd += w_in_r[4 * k] * v.x + w_in_r[4 * k + 1] * v.y
              + w_in_r[4 * k + 2] * v.z + w_in_r[4 * k + 3] * v.w;
        }
        xz[t * 160 + e_in] = sd * rsqrtf(ss * (1.f / 40.f) + 1e-5f);
      }
      if (tid < 160) xin[tid] = src[t0 * 40 + tid];
    } else {
      // every wave polls (wave-uniform); loads are program-ordered after the
      // observed flag -> guaranteed fresh (producer B5-drained before flag)
      while (__hip_atomic_load(flag_prev, __ATOMIC_RELAXED,
                               __HIP_MEMORY_SCOPE_AGENT) <= c)
        __builtin_amdgcn_s_sleep(1);
#pragma unroll
      for (int tt = 0; tt < 2; ++tt) {
        const int t = tA + 2 * tt;
        const u64* sp = (const u64*)(src + (t0 + t) * 40);
        float ss = 0.f, sd = 0.f;
#pragma unroll
        for (int k = 0; k < 20; ++k) {
          u64 a = __hip_atomic_load(sp + k, __ATOMIC_RELAXED,
                                    __HIP_MEMORY_SCOPE_AGENT);
          float v0 = unplo(a), v1 = unphi(a);
          ss += v0 * v0 + v1 * v1;
          sd += w_in_r[2 * k] * v0 + w_in_r[2 * k + 1] * v1;
        }
        xz[t * 160 + e_in] = sd * rsqrtf(ss * (1.f / 40.f) + 1e-5f);
      }
      if (tid < 80) {
        u64 a = __hip_atomic_load((const u64*)(src + t0 * 40) + tid,
                                  __ATOMIC_RELAXED, __HIP_MEMORY_SCOPE_AGENT);
        xin[2 * tid] = unplo(a);
        xin[2 * tid + 1] = unphi(a);
      }
    }
    __syncthreads();                                   // B1: xz, xin ready

    // ---- causal depthwise conv(4) + silu ----
    {
      float acc = cb;
#pragma unroll
      for (int j = 0; j < 4; ++j) {
        int lt = t_c - 3 + j;
        float xv = (lt >= 0) ? xz[lt * 160 + d_c] : xhist[(lt + 3) * 80 + d_c];
        acc += cw[j] * xv;
      }
      xs[t_c * 80 + d_c] = acc / (1.f + __expf(-acc));
    }
    __syncthreads();                                   // B2: xs ready

    // ---- x_proj: pair half-dots + shfl merge; idle threads refresh xhist ----
    if (p_x < 140) {
      const float4* xp = (const float4*)&xs[t_x * 80 + halfp * 40];
      float s = 0.f;
#pragma unroll
      for (int k = 0; k < 10; ++k) {
        float4 v = xp[k];
        s += w_xp_r[4 * k] * v.x + w_xp_r[4 * k + 1] * v.y
           + w_xp_r[4 * k + 2] * v.z + w_xp_r[4 * k + 3] * v.w;
      }
      s += __shfl_xor(s, 1);
      if (halfp == 0) dbc[t_x * 36 + e_x] = s;
    } else {
      for (int k = tid - 280; k < 240; k += 40)
        xhist[k] = xz[(1 + k / 80) * 160 + (k % 80)];
    }
    __syncthreads();                                   // B3: dbc ready

    // ---- selective scan; dt inline; state in regs ----
#pragma unroll
    for (int t = 0; t < CH; ++t) {
      const float* db = &dbc[t * 36];
      float sdt = dtb + db[0] * dtw0 + db[1] * dtw1 + db[2] * dtw2;
      float dtval = (sdt > 15.f) ? sdt : __logf(1.f + __expf(sdt));
      float xval = xs[t * 80 + d_ch];
      float part = 0.f;
#pragma unroll
      for (int j = 0; j < 4; ++j) {
        int s_i = qq * 4 + j;
        float Bv = db[3 + s_i];
        float Cv = db[19 + s_i];
        hst[j] = __expf(dtval * negA[j]) * hst[j] + dtval * Bv * xval;
        part += hst[j] * Cv;
      }
      part += __shfl_xor(part, 1);
      part += __shfl_xor(part, 2);
      if (qq == 0) {
        float yv = part + xval * wD;
        float z = xz[t * 160 + 80 + d_ch];
        yb[t * 80 + d_ch] = yv * z / (1.f + __expf(-z));
      }
    }
    __syncthreads();                                   // B4: yb ready

    // ---- out_proj + residual -> paired dwordx2 coherent stores ----
    {
      const float4* yp = (const float4*)&yb[t_o * 80 + halfp * 40];
      float s = 0.f;
#pragma unroll
      for (int k = 0; k < 10; ++k) {
        float4 v = yp[k];
        s += w_out_r[4 * k] * v.x + w_out_r[4 * k + 1] * v.y
           + w_out_r[4 * k + 2] * v.z + w_out_r[4 * k + 3] * v.w;
      }
      s += __shfl_xor(s, 1);
      float r = xin[p_o] + s;          // valid on pair leaders (halfp==0)
      float r2 = __shfl_xor(r, 2);     // leader tid+2's value (p_o+1)
      if ((tid & 3) == 0)              // even p_o leaders store the pair
        __hip_atomic_store((u64*)(dst + t0 * 40 + p_o), pack2(r, r2),
                           __ATOMIC_RELAXED, __HIP_MEMORY_SCOPE_AGENT);
    }
    __syncthreads();        // B5: drains vmcnt -> all stores acked at IF$
    if (tid == 0)
      __hip_atomic_store(flag_cur, c + 1, __ATOMIC_RELAXED,
                         __HIP_MEMORY_SCOPE_AGENT);
  }
}

// ---- context side of cross-attn: cn = LN(x_final), kv = cn @ ca_kv_w^T ----
__global__ __launch_bounds__(64) void kv_kernel(
    const float* __restrict__ xfin,
    const float* __restrict__ lnc_w, const float* __restrict__ lnc_b,
    const float* __restrict__ kv_w,
    float* __restrict__ kbuf, float* __restrict__ vbuf)
{
  int t = blockIdx.x;
  int lane = threadIdx.x;
  float x = (lane < 40) ? xfin[t * 40 + lane] : 0.f;
  float s = x;
#pragma unroll
  for (int o = 32; o >= 1; o >>= 1) s += __shfl_xor(s, o);
  float m = s * (1.f / 40.f);
  float dv = (lane < 40) ? (x - m) : 0.f;
  float v2 = dv * dv;
#pragma unroll
  for (int o = 32; o >= 1; o >>= 1) v2 += __shfl_xor(v2, o);
  float rstd = rsqrtf(v2 * (1.f / 40.f) + 1e-5f);
  __shared__ float cn[40];
  if (lane < 40) cn[lane] = dv * rstd * lnc_w[lane] + lnc_b[lane];
  __syncthreads();
  for (int e = lane; e < 80; e += 64) {
    float acc = 0.f;
#pragma unroll
    for (int d = 0; d < 40; ++d) acc += cn[d] * kv_w[e * 40 + d];
    if (e < 40) kbuf[t * 40 + e] = acc;
    else vbuf[t * 40 + (e - 40)] = acc;
  }
}

// ---- per-query decode: wave-pair split; all weight/k/v addresses uniform ----
__global__ __launch_bounds__(256) void query_kernel(
    const float* __restrict__ qry,
    const float* __restrict__ pe_w, const float* __restrict__ pe_b,
    const float* __restrict__ lnq_w, const float* __restrict__ lnq_b,
    const float* __restrict__ qw,
    const float* __restrict__ ow, const float* __restrict__ ob,
    const float* __restrict__ flw, const float* __restrict__ flb,
    const float* __restrict__ w1, const float* __restrict__ b1,
    const float* __restrict__ w2, const float* __restrict__ b2,
    const float* __restrict__ outw, const float* __restrict__ outb,
    const float* __restrict__ kbuf, const float* __restrict__ vbuf,
    float* __restrict__ out)
{
  const int tid = threadIdx.x;
  const int h = __builtin_amdgcn_readfirstlane((tid >> 6) & 1);  // wave in pair
  const int pj = tid >> 7;               // wave-pair 0/1
  const int lane = tid & 63;
  const int n = blockIdx.x * 128 + pj * 64 + lane;   // query id
  const int ptn = tid ^ 64;              // partner thread (other wave in pair)
  __shared__ float colbuf[40 * 256];
  __shared__ float redm[256], redl[256];

  const float qx = qry[n * 3 + 0], qy = qry[n * 3 + 1], qz = qry[n * 3 + 2];

  // ---- PE-MLP, octaves split by wave half ----
  float qp[40];
#pragma unroll
  for (int d = 0; d < 40; ++d) qp[d] = 0.f;
#pragma unroll
  for (int jj = 0; jj < 4; ++jj) {
    const int j = h * 4 + jj;
    float f = 3.14159265358979323846f * (float)(1 << j);
    float sx, cx, sy, cy, sz, cz;
    __sincosf(qx * f, &sx, &cx);
    __sincosf(qy * f, &sy, &cy);
    __sincosf(qz * f, &sz, &cz);
#pragma unroll
    for (int d = 0; d < 40; ++d) {
      const float* r = pe_w + d * 51;
      qp[d] += sx * r[j] + sy * r[j + 8] + sz * r[j + 16]
             + cx * r[j + 24] + cy * r[j + 32] + cz * r[j + 40];
    }
  }
#pragma unroll
  for (int d = 0; d < 40; ++d) colbuf[d * 256 + tid] = qp[d];
  __syncthreads();                                    // B1
  float qe[40];
#pragma unroll
  for (int d = 0; d < 40; ++d) {
    const float* r = pe_w + d * 51;
    qe[d] = pe_b[d] + qp[d] + colbuf[d * 256 + ptn]
          + qx * r[48] + qy * r[49] + qz * r[50];
  }
  __syncthreads();                                    // B2 (colbuf free)

  // ---- LN(qe) -> qn regs; q-proj split by d-half ----
  float qn[40];
  {
    float m = 0.f;
#pragma unroll
    for (int d = 0; d < 40; ++d) m += qe[d];
    m *= (1.f / 40.f);
    float var = 0.f;
#pragma unroll
    for (int d = 0; d < 40; ++d) { float dv = qe[d] - m; var += dv * dv; }
    float rstd = rsqrtf(var * (1.f / 40.f) + 1e-5f);
#pragma unroll
    for (int d = 0; d < 40; ++d) qn[d] = (qe[d] - m) * rstd * lnq_w[d] + lnq_b[d];
  }
  float qnh[20];
#pragma unroll
  for (int dd = 0; dd < 20; ++dd) qnh[dd] = h ? qn[dd + 20] : qn[dd];
  float q[40];
#pragma unroll
  for (int e = 0; e < 40; ++e) q[e] = 0.f;
#pragma unroll 1
  for (int dd = 0; dd < 20; ++dd) {
    const float qv = qnh[dd];
    const int d = h * 20 + dd;
#pragma unroll
    for (int e = 0; e < 40; ++e) q[e] += qv * qw[e * 40 + d];
  }
#pragma unroll
  for (int e = 0; e < 40; ++e) colbuf[e * 256 + tid] = q[e];
  __syncthreads();                                    // B3
#pragma unroll
  for (int e = 0; e < 40; ++e) q[e] += colbuf[e * 256 + ptn];
  __syncthreads();                                    // B4 (colbuf free)

  // ---- flash attention over this wave's 200 tokens (uniform addresses) ----
  float acc[40];
#pragma unroll
  for (int d = 0; d < 40; ++d) acc[d] = 0.f;
  float mx = -1e30f, l = 0.f;
  const float scale = 0.15811388300841897f;  // 40^-0.5
  const int tbeg = h * 200, tend = tbeg + 200;
#pragma unroll 1
  for (int t = tbeg; t < tend; ++t) {
    const float4* kr = (const float4*)(kbuf + t * 40);
    float s0 = 0.f, s1 = 0.f, s2 = 0.f, s3 = 0.f;
#pragma unroll
    for (int k = 0; k < 10; ++k) {
      float4 k4 = kr[k];
      s0 += q[4 * k] * k4.x; s1 += q[4 * k + 1] * k4.y;
      s2 += q[4 * k + 2] * k4.z; s3 += q[4 * k + 3] * k4.w;
    }
    float s = ((s0 + s1) + (s2 + s3)) * scale;
    if (s > mx) {
      float corr = __expf(mx - s);
      l *= corr;
#pragma unroll
      for (int d = 0; d < 40; ++d) acc[d] *= corr;
      mx = s;
    }
    float p = __expf(s - mx);
    l += p;
    const float4* vr = (const float4*)(vbuf + t * 40);
#pragma unroll
    for (int k = 0; k < 10; ++k) {
      float4 v4 = vr[k];
      acc[4 * k] += p * v4.x; acc[4 * k + 1] += p * v4.y;
      acc[4 * k + 2] += p * v4.z; acc[4 * k + 3] += p * v4.w;
    }
  }
  // merge across the wave pair via LDS (symmetric)
#pragma unroll
  for (int d = 0; d < 40; ++d) colbuf[d * 256 + tid] = acc[d];
  redm[tid] = mx; redl[tid] = l;
  __syncthreads();                                    // B5
  float lat[40];
  {
    float m2 = redm[ptn];
    float l2 = redl[ptn];
    float nm = fmaxf(mx, m2);
    float a = __expf(mx - nm), b = __expf(m2 - nm);
    float lm = l * a + l2 * b;
    float linv = 1.f / lm;
#pragma unroll
    for (int d = 0; d < 40; ++d)
      lat[d] = (acc[d] * a + colbuf[d * 256 + ptn] * b) * linv;
  }
  __syncthreads();                                    // B6 (colbuf free)

  // ---- lat2 = lat @ ca_out_w^T + ob, split by d-half ----
  float lath[20];
#pragma unroll
  for (int dd = 0; dd < 20; ++dd) lath[dd] = h ? lat[dd + 20] : lat[dd];
  float lp[40];
#pragma unroll
  for (int e = 0; e < 40; ++e) lp[e] = 0.f;
#pragma unroll 1
  for (int dd = 0; dd < 20; ++dd) {
    const float lv = lath[dd];
    const int d = h * 20 + dd;
#pragma unroll
    for (int e = 0; e < 40; ++e) lp[e] += lv * ow[e * 40 + d];
  }
#pragma unroll
  for (int e = 0; e < 40; ++e) colbuf[e * 256 + tid] = lp[e];
  __syncthreads();                                    // B7
  float lat2[40];
#pragma unroll
  for (int e = 0; e < 40; ++e) lat2[e] = ob[e] + lp[e] + colbuf[e * 256 + ptn];
  __syncthreads();                                    // B8 (colbuf free)

  // ---- LN + FFN (e-range split by wave half) ----
  float hh[40];
  {
    float m = 0.f;
#pragma unroll
    for (int d = 0; d < 40; ++d) m += lat2[d];
    m *= (1.f / 40.f);
    float var = 0.f;
#pragma unroll
    for (int d = 0; d < 40; ++d) { float dv = lat2[d] - m; var += dv * dv; }
    float rstd = rsqrtf(var * (1.f / 40.f) + 1e-5f);
#pragma unroll
    for (int d = 0; d < 40; ++d) hh[d] = (lat2[d] - m) * rstd * flw[d] + flb[d];
  }
  float ff[40];
#pragma unroll
  for (int d = 0; d < 40; ++d) ff[d] = 0.f;
#pragma unroll 1
  for (int ee = 0; ee < 80; ++ee) {
    const int e = h * 80 + ee;
    const float* r1 = w1 + e * 40;
    const float* r2 = w1 + (160 + e) * 40;
    float a0 = 0.f, a1 = 0.f;
#pragma unroll
    for (int d = 0; d < 40; ++d) { a0 += hh[d] * r1[d]; a1 += hh[d] * r2[d]; }
    float x1 = a0 + b1[e];
    float g = a1 + b1[160 + e];
    float tv = x1 * (0.5f * g * (1.f + erff(g * 0.70710678118654752f)));
#pragma unroll
    for (int d = 0; d < 40; ++d) ff[d] += tv * w2[d * 160 + e];
  }
#pragma unroll
  for (int d = 0; d < 40; ++d) colbuf[d * 256 + tid] = ff[d];
  __syncthreads();                                    // B9
  float r = outb[0];
#pragma unroll
  for (int d = 0; d < 40; ++d) {
    float f = ff[d] + colbuf[d * 256 + ptn] + b2[d];
    r += (lat2[d] + f) * outw[d];
  }
  if (h == 0) out[n] = r;
}

extern "C" void kernel_launch(void* const* d_in, const int* in_sizes, int n_in,
                              void* d_out, int out_size, void* d_ws, size_t ws_size,
                              hipStream_t stream) {
  const float* mash   = (const float*)d_in[0];
  const float* qry    = (const float*)d_in[1];
  const float* lnw    = (const float*)d_in[2];
  const float* linw   = (const float*)d_in[3];
  const float* lconvw = (const float*)d_in[4];
  const float* lconvb = (const float*)d_in[5];
  const float* lxpw   = (const float*)d_in[6];
  const float* ldtw   = (const float*)d_in[7];
  const float* ldtb   = (const float*)d_in[8];
  const float* lAlog  = (const float*)d_in[9];
  const float* lD     = (const float*)d_in[10];
  const float* loutw  = (const float*)d_in[11];
  const float* pew    = (const float*)d_in[12];
  const float* peb    = (const float*)d_in[13];
  const float* lnqw   = (const float*)d_in[14];
  const float* lnqb   = (const float*)d_in[15];
  const float* lncw   = (const float*)d_in[16];
  const float* lncb   = (const float*)d_in[17];
  const float* qw     = (const float*)d_in[18];
  const float* kvw    = (const float*)d_in[19];
  const float* oww    = (const float*)d_in[20];
  const float* owb    = (const float*)d_in[21];
  const float* flnw   = (const float*)d_in[22];
  const float* flnb   = (const float*)d_in[23];
  const float* w1     = (const float*)d_in[24];
  const float* b1     = (const float*)d_in[25];
  const float* w2     = (const float*)d_in[26];
  const float* b2     = (const float*)d_in[27];
  const float* outw   = (const float*)d_in[28];
  const float* outb   = (const float*)d_in[29];

  // ws layout (f32 elements): xb0[16000] xb1[16000] k[16000] v[16000] flags
  float* wsf = (float*)d_ws;
  float* xb0 = wsf;
  float* xb1 = wsf + 16000;
  float* kbuf = wsf + 32000;
  float* vbuf = wsf + 48000;
  int* flags = (int*)(wsf + 64000);

  hipLaunchKernelGGL(init_flags, dim3(16), dim3(256), 0, stream, flags);
  hipLaunchKernelGGL(mamba_pipe, dim3(256), dim3(TPB1), 0, stream,
                     mash, lnw, linw, lconvw, lconvb, lxpw, ldtw, ldtb, lAlog,
                     lD, loutw, xb0, xb1, flags);
  // layer 255 (odd) writes xb1
  hipLaunchKernelGGL(kv_kernel, dim3(400), dim3(64), 0, stream,
                     xb1, lncw, lncb, kvw, kbuf, vbuf);
  hipLaunchKernelGGL(query_kernel, dim3(512), dim3(256), 0, stream,
                     qry, pew, peb, lnqw, lnqb, qw, oww, owb, flnw, flnb,
                     w1, b1, w2, b2, outw, outb, kbuf, vbuf, (float*)d_out);
}

// Round 9
// 2115.137 us; speedup vs baseline: 1.9754x; 1.0249x over previous
//
#include <hip/hip_runtime.h>

// ---------------------------------------------------------------------------
// MashDecoderV2: 256-layer mamba stack (L=400, D=40) + 65536-query cross-attn
// decoder. f32 throughout (threshold 1.56e-2; current absmax 2e-3).
//
// Round-9:
// Stage 1: mamba loop byte-identical to R8 (measured floor 1739us, T_stage
//   4.9us). NEW: grid 256->461; blocks >=256 are PE blocks (zero LDS, no
//   barriers) that compute each query's PE-MLP -> LN -> q-projection and
//   store q transposed to ws. They co-reside in the ~75% idle wave slots of
//   the mamba CUs (in-order dispatch: layer blocks 0..255 land first, 1/CU),
//   so this work runs under mamba's latency shadow.
// Stage 2: query_fast: 4-way token split (4 waves per query-group, 100
//   tokens each, 2-token ILP steps), precomputed q, 4-way LDS-column merges.
// Fallback (ws too small): R8 query kernel with PE inside.
// ---------------------------------------------------------------------------

#define CH 4
#define NCHUNK 100       // 400 / CH
#define TPB1 320

typedef unsigned long long u64;

__device__ __forceinline__ u64 pack2(float a, float b) {
  return ((u64)__float_as_uint(b) << 32) | (u64)__float_as_uint(a);
}
__device__ __forceinline__ float unplo(u64 a) {
  return __uint_as_float((unsigned)a);
}
__device__ __forceinline__ float unphi(u64 a) {
  return __uint_as_float((unsigned)(a >> 32));
}

__global__ void init_flags(int* __restrict__ flags) {
  int i = blockIdx.x * 256 + threadIdx.x;
  if (i < 256 * 16) flags[i] = 0;
}

__global__ __launch_bounds__(TPB1) void mamba_pipe(
    const float* __restrict__ mash,
    const float* __restrict__ g_norm_w,   // (256,40)
    const float* __restrict__ g_in_w,     // (256,160,40)
    const float* __restrict__ g_conv_w,   // (256,80,4)
    const float* __restrict__ g_conv_b,   // (256,80)
    const float* __restrict__ g_xp_w,     // (256,35,80)
    const float* __restrict__ g_dt_w,     // (256,80,3)
    const float* __restrict__ g_dt_b,     // (256,80)
    const float* __restrict__ g_alog,     // (256,80,16)
    const float* __restrict__ g_D,        // (256,80)
    const float* __restrict__ g_out_w,    // (256,40,80)
    float* __restrict__ xb0,
    float* __restrict__ xb1,
    int* __restrict__ flags,
    // PE-block inputs (blocks >= 256)
    const float* __restrict__ qry,
    const float* __restrict__ pe_w, const float* __restrict__ pe_b,
    const float* __restrict__ lnq_w, const float* __restrict__ lnq_b,
    const float* __restrict__ qw,
    float* __restrict__ qstore)           // q_t[e*65536 + n]
{
  const int tid = threadIdx.x;

  // ---------------- PE blocks: query preprocessing under mamba's shadow ----
  if (blockIdx.x >= 256) {
    const int n = (blockIdx.x - 256) * TPB1 + tid;
    if (n < 65536) {
      const float qx = qry[n * 3 + 0], qy = qry[n * 3 + 1], qz = qry[n * 3 + 2];
      float qe[40];
#pragma unroll
      for (int d = 0; d < 40; ++d) qe[d] = pe_b[d];
#pragma unroll 1
      for (int j = 0; j < 8; ++j) {
        float f = 3.14159265358979323846f * (float)(1 << j);
        float sx, cx, sy, cy, sz, cz;
        __sincosf(qx * f, &sx, &cx);
        __sincosf(qy * f, &sy, &cy);
        __sincosf(qz * f, &sz, &cz);
#pragma unroll
        for (int d = 0; d < 40; ++d) {
          const float* r = pe_w + d * 51;
          qe[d] += sx * r[j] + sy * r[j + 8] + sz * r[j + 16]
                 + cx * r[j + 24] + cy * r[j + 32] + cz * r[j + 40];
        }
      }
#pragma unroll
      for (int d = 0; d < 40; ++d) {
        const float* r = pe_w + d * 51;
        qe[d] += qx * r[48] + qy * r[49] + qz * r[50];
      }
      // LN -> qn (registers)
      float qn[40];
      {
        float m = 0.f;
#pragma unroll
        for (int d = 0; d < 40; ++d) m += qe[d];
        m *= (1.f / 40.f);
        float var = 0.f;
#pragma unroll
        for (int d = 0; d < 40; ++d) { float dv = qe[d] - m; var += dv * dv; }
        float rstd = rsqrtf(var * (1.f / 40.f) + 1e-5f);
#pragma unroll
        for (int d = 0; d < 40; ++d)
          qn[d] = (qe[d] - m) * rstd * lnq_w[d] + lnq_b[d];
      }
      // q-proj, fully unrolled (constant reg indices; qw scalar loads)
      float q[40];
#pragma unroll
      for (int e = 0; e < 40; ++e) {
        const float* r = qw + e * 40;
        float s = 0.f;
#pragma unroll
        for (int d = 0; d < 40; ++d) s += qn[d] * r[d];
        q[e] = s;
      }
#pragma unroll
      for (int e = 0; e < 40; ++e) qstore[e * 65536 + n] = q[e];
    }
    return;
  }

  // ---------------- layer blocks: R8 mamba loop (unchanged) ----------------
  const int layer = blockIdx.x;

  __shared__ float xin[160];
  __shared__ float xz[640];
  __shared__ float xs[320];
  __shared__ float dbc[144];        // stride 36
  __shared__ float yb[320];
  __shared__ float xhist[240];      // conv tail

  const int e_in = tid % 160;
  const int tA = tid / 160;
  float w_in_r[40];                 // in_proj row with rmsnorm weight folded
  {
    const float4* g = (const float4*)(g_in_w + layer * 6400 + e_in * 40);
    const float4* nw = (const float4*)(g_norm_w + layer * 40);
#pragma unroll
    for (int k = 0; k < 10; ++k) {
      float4 v = g[k];
      float4 n = nw[k];
      w_in_r[4 * k] = v.x * n.x; w_in_r[4 * k + 1] = v.y * n.y;
      w_in_r[4 * k + 2] = v.z * n.z; w_in_r[4 * k + 3] = v.w * n.w;
    }
  }
  const int d_c = tid % 80;
  const int t_c = tid / 80;
  float cw[4]; float cb;
  {
    float4 v = *(const float4*)(g_conv_w + layer * 320 + d_c * 4);
    cw[0] = v.x; cw[1] = v.y; cw[2] = v.z; cw[3] = v.w;
    cb = g_conv_b[layer * 80 + d_c];
  }
  const int halfp = tid & 1;
  const int p_x = tid >> 1;              // <140 active for x_proj
  const int t_x = p_x / 35, e_x = p_x % 35;
  float w_xp_r[40];
  if (p_x < 140) {
    const float4* g = (const float4*)(g_xp_w + layer * 2800 + e_x * 80 + halfp * 40);
#pragma unroll
    for (int k = 0; k < 10; ++k) {
      float4 v = g[k];
      w_xp_r[4 * k] = v.x; w_xp_r[4 * k + 1] = v.y;
      w_xp_r[4 * k + 2] = v.z; w_xp_r[4 * k + 3] = v.w;
    }
  }
  const int d_ch = tid >> 2;
  const int qq = tid & 3;
  float negA[4], hst[4];
  {
    float4 v = *(const float4*)(g_alog + layer * 1280 + tid * 4);
    negA[0] = -__expf(v.x); negA[1] = -__expf(v.y);
    negA[2] = -__expf(v.z); negA[3] = -__expf(v.w);
    hst[0] = hst[1] = hst[2] = hst[3] = 0.f;
  }
  const float dtw0 = g_dt_w[layer * 240 + d_ch * 3 + 0];
  const float dtw1 = g_dt_w[layer * 240 + d_ch * 3 + 1];
  const float dtw2 = g_dt_w[layer * 240 + d_ch * 3 + 2];
  const float dtb = g_dt_b[layer * 80 + d_ch];
  const float wD = g_D[layer * 80 + d_ch];
  const int p_o = tid >> 1;
  const int t_o = p_o / 40, e_o = p_o % 40;
  float w_out_r[40];
  {
    const float4* g = (const float4*)(g_out_w + layer * 3200 + e_o * 80 + halfp * 40);
#pragma unroll
    for (int k = 0; k < 10; ++k) {
      float4 v = g[k];
      w_out_r[4 * k] = v.x; w_out_r[4 * k + 1] = v.y;
      w_out_r[4 * k + 2] = v.z; w_out_r[4 * k + 3] = v.w;
    }
  }

  for (int i = tid; i < 240; i += TPB1) xhist[i] = 0.f;
  __syncthreads();

  const float* src = (layer == 0) ? mash : ((layer & 1) ? xb0 : xb1);
  float* dst = (layer & 1) ? xb1 : xb0;
  int* flag_prev = flags + (layer - 1) * 16;
  int* flag_cur = flags + layer * 16;

  for (int c = 0; c < NCHUNK; ++c) {
    const int t0 = c * CH;

    // ---- Phase A: ordered acquire + in_proj (rmsnorm folded) ----
    if (layer == 0) {
#pragma unroll
      for (int tt = 0; tt < 2; ++tt) {
        const int t = tA + 2 * tt;
        const float4* sp = (const float4*)(src + (t0 + t) * 40);
        float ss = 0.f, sd = 0.f;
#pragma unroll
        for (int k = 0; k < 10; ++k) {
          float4 v = sp[k];
          ss += v.x * v.x + v.y * v.y + v.z * v.z + v.w * v.w;
          sd += w_in_r[4 * k] * v.x + w_in_r[4 * k + 1] * v.y
              + w_in_r[4 * k + 2] * v.z + w_in_r[4 * k + 3] * v.w;
        }
        xz[t * 160 + e_in] = sd * rsqrtf(ss * (1.f / 40.f) + 1e-5f);
      }
      if (tid < 160) xin[tid] = src[t0 * 40 + tid];
    } else {
      // every wave polls (wave-uniform); loads are program-ordered after the
      // observed flag -> guaranteed fresh (producer B5-drained before flag)
      while (__hip_atomic_load(flag_prev, __ATOMIC_RELAXED,
                               __HIP_MEMORY_SCOPE_AGENT) <= c)
        __builtin_amdgcn_s_sleep(1);
#pragma unroll
      for (int tt = 0; tt < 2; ++tt) {
        const int t = tA + 2 * tt;
        const u64* sp = (const u64*)(src + (t0 + t) * 40);
        float ss = 0.f, sd = 0.f;
#pragma unroll
        for (int k = 0; k < 20; ++k) {
          u64 a = __hip_atomic_load(sp + k, __ATOMIC_RELAXED,
                                    __HIP_MEMORY_SCOPE_AGENT);
          float v0 = unplo(a), v1 = unphi(a);
          ss += v0 * v0 + v1 * v1;
          sd += w_in_r[2 * k] * v0 + w_in_r[2 * k + 1] * v1;
        }
        xz[t * 160 + e_in] = sd * rsqrtf(ss * (1.f / 40.f) + 1e-5f);
      }
      if (tid < 80) {
        u64 a = __hip_atomic_load((const u64*)(src + t0 * 40) + tid,
                                  __ATOMIC_RELAXED, __HIP_MEMORY_SCOPE_AGENT);
        xin[2 * tid] = unplo(a);
        xin[2 * tid + 1] = unphi(a);
      }
    }
    __syncthreads();                                   // B1: xz, xin ready

    // ---- causal depthwise conv(4) + silu ----
    {
      float acc = cb;
#pragma unroll
      for (int j = 0; j < 4; ++j) {
        int lt = t_c - 3 + j;
        float xv = (lt >= 0) ? xz[lt * 160 + d_c] : xhist[(lt + 3) * 80 + d_c];
        acc += cw[j] * xv;
      }
      xs[t_c * 80 + d_c] = acc / (1.f + __expf(-acc));
    }
    __syncthreads();                                   // B2: xs ready

    // ---- x_proj: pair half-dots + shfl merge; idle threads refresh xhist ----
    if (p_x < 140) {
      const float4* xp = (const float4*)&xs[t_x * 80 + halfp * 40];
      float s = 0.f;
#pragma unroll
      for (int k = 0; k < 10; ++k) {
        float4 v = xp[k];
        s += w_xp_r[4 * k] * v.x + w_xp_r[4 * k + 1] * v.y
           + w_xp_r[4 * k + 2] * v.z + w_xp_r[4 * k + 3] * v.w;
      }
      s += __shfl_xor(s, 1);
      if (halfp == 0) dbc[t_x * 36 + e_x] = s;
    } else {
      for (int k = tid - 280; k < 240; k += 40)
        xhist[k] = xz[(1 + k / 80) * 160 + (k % 80)];
    }
    __syncthreads();                                   // B3: dbc ready

    // ---- selective scan; dt inline; state in regs ----
#pragma unroll
    for (int t = 0; t < CH; ++t) {
      const float* db = &dbc[t * 36];
      float sdt = dtb + db[0] * dtw0 + db[1] * dtw1 + db[2] * dtw2;
      float dtval = (sdt > 15.f) ? sdt : __logf(1.f + __expf(sdt));
      float xval = xs[t * 80 + d_ch];
      float part = 0.f;
#pragma unroll
      for (int j = 0; j < 4; ++j) {
        int s_i = qq * 4 + j;
        float Bv = db[3 + s_i];
        float Cv = db[19 + s_i];
        hst[j] = __expf(dtval * negA[j]) * hst[j] + dtval * Bv * xval;
        part += hst[j] * Cv;
      }
      part += __shfl_xor(part, 1);
      part += __shfl_xor(part, 2);
      if (qq == 0) {
        float yv = part + xval * wD;
        float z = xz[t * 160 + 80 + d_ch];
        yb[t * 80 + d_ch] = yv * z / (1.f + __expf(-z));
      }
    }
    __syncthreads();                                   // B4: yb ready

    // ---- out_proj + residual -> paired dwordx2 coherent stores ----
    {
      const float4* yp = (const float4*)&yb[t_o * 80 + halfp * 40];
      float s = 0.f;
#pragma unroll
      for (int k = 0; k < 10; ++k) {
        float4 v = yp[k];
        s += w_out_r[4 * k] * v.x + w_out_r[4 * k + 1] * v.y
           + w_out_r[4 * k + 2] * v.z + w_out_r[4 * k + 3] * v.w;
      }
      s += __shfl_xor(s, 1);
      float r = xin[p_o] + s;          // valid on pair leaders (halfp==0)
      float r2 = __shfl_xor(r, 2);     // leader tid+2's value (p_o+1)
      if ((tid & 3) == 0)              // even p_o leaders store the pair
        __hip_atomic_store((u64*)(dst + t0 * 40 + p_o), pack2(r, r2),
                           __ATOMIC_RELAXED, __HIP_MEMORY_SCOPE_AGENT);
    }
    __syncthreads();        // B5: drains vmcnt -> all stores acked at IF$
    if (tid == 0)
      __hip_atomic_store(flag_cur, c + 1, __ATOMIC_RELAXED,
                         __HIP_MEMORY_SCOPE_AGENT);
  }
}

// ---- context side of cross-attn: cn = LN(x_final), kv = cn @ ca_kv_w^T ----
__global__ __launch_bounds__(64) void kv_kernel(
    const float* __restrict__ xfin,
    const float* __restrict__ lnc_w, const float* __restrict__ lnc_b,
    const float* __restrict__ kv_w,
    float* __restrict__ kbuf, float* __restrict__ vbuf)
{
  int t = blockIdx.x;
  int lane = threadIdx.x;
  float x = (lane < 40) ? xfin[t * 40 + lane] : 0.f;
  float s = x;
#pragma unroll
  for (int o = 32; o >= 1; o >>= 1) s += __shfl_xor(s, o);
  float m = s * (1.f / 40.f);
  float dv = (lane < 40) ? (x - m) : 0.f;
  float v2 = dv * dv;
#pragma unroll
  for (int o = 32; o >= 1; o >>= 1) v2 += __shfl_xor(v2, o);
  float rstd = rsqrtf(v2 * (1.f / 40.f) + 1e-5f);
  __shared__ float cn[40];
  if (lane < 40) cn[lane] = dv * rstd * lnc_w[lane] + lnc_b[lane];
  __syncthreads();
  for (int e = lane; e < 80; e += 64) {
    float acc = 0.f;
#pragma unroll
    for (int d = 0; d < 40; ++d) acc += cn[d] * kv_w[e * 40 + d];
    if (e < 40) kbuf[t * 40 + e] = acc;
    else vbuf[t * 40 + (e - 40)] = acc;
  }
}

// ---- fast query decode: precomputed q, 4-way token split per query ----
__global__ __launch_bounds__(256) void query_fast(
    const float* __restrict__ qstore,    // q_t[e*65536 + n]
    const float* __restrict__ ow, const float* __restrict__ ob,
    const float* __restrict__ flw, const float* __restrict__ flb,
    const float* __restrict__ w1, const float* __restrict__ b1,
    const float* __restrict__ w2, const float* __restrict__ b2,
    const float* __restrict__ outw, const float* __restrict__ outb,
    const float* __restrict__ kbuf, const float* __restrict__ vbuf,
    float* __restrict__ out)
{
  const int tid = threadIdx.x;
  const int h = __builtin_amdgcn_readfirstlane((tid >> 6) & 3);  // wave 0..3
  const int lane = tid & 63;
  const int n = blockIdx.x * 64 + lane;
  const int p1 = tid ^ 64, p2 = tid ^ 128, p3 = tid ^ 192;
  __shared__ float colbuf[40 * 256];     // 40KB: merge staging (reused)

  // load precomputed q (coalesced per e-plane)
  float q[40];
#pragma unroll
  for (int e = 0; e < 40; ++e) q[e] = qstore[e * 65536 + n];

  // flash attention over this wave's 100 tokens, 2 tokens per step (ILP)
  float acc[40];
#pragma unroll
  for (int d = 0; d < 40; ++d) acc[d] = 0.f;
  float mx = -1e30f, l = 0.f;
  const float scale = 0.15811388300841897f;  // 40^-0.5
  const int tbeg = h * 100;
#pragma unroll 1
  for (int t = tbeg; t < tbeg + 100; t += 2) {
    const float4* ka = (const float4*)(kbuf + t * 40);
    const float4* kb = (const float4*)(kbuf + t * 40 + 40);
    float a0 = 0.f, a1 = 0.f, b0 = 0.f, b1s = 0.f;
#pragma unroll
    for (int k = 0; k < 10; ++k) {
      float4 k4 = ka[k];
      float4 j4 = kb[k];
      a0 += q[4 * k] * k4.x + q[4 * k + 1] * k4.y;
      a1 += q[4 * k + 2] * k4.z + q[4 * k + 3] * k4.w;
      b0 += q[4 * k] * j4.x + q[4 * k + 1] * j4.y;
      b1s += q[4 * k + 2] * j4.z + q[4 * k + 3] * j4.w;
    }
    float sa = (a0 + a1) * scale;
    float sb = (b0 + b1s) * scale;
    // sequential online-softmax updates (dots above carried the ILP)
    {
      if (sa > mx) {
        float corr = __expf(mx - sa);
        l *= corr;
#pragma unroll
        for (int d = 0; d < 40; ++d) acc[d] *= corr;
        mx = sa;
      }
      float p = __expf(sa - mx);
      l += p;
      const float4* vr = (const float4*)(vbuf + t * 40);
#pragma unroll
      for (int k = 0; k < 10; ++k) {
        float4 v4 = vr[k];
        acc[4 * k] += p * v4.x; acc[4 * k + 1] += p * v4.y;
        acc[4 * k + 2] += p * v4.z; acc[4 * k + 3] += p * v4.w;
      }
    }
    {
      if (sb > mx) {
        float corr = __expf(mx - sb);
        l *= corr;
#pragma unroll
        for (int d = 0; d < 40; ++d) acc[d] *= corr;
        mx = sb;
      }
      float p = __expf(sb - mx);
      l += p;
      const float4* vr = (const float4*)(vbuf + (t + 1) * 40);
#pragma unroll
      for (int k = 0; k < 10; ++k) {
        float4 v4 = vr[k];
        acc[4 * k] += p * v4.x; acc[4 * k + 1] += p * v4.y;
        acc[4 * k + 2] += p * v4.z; acc[4 * k + 3] += p * v4.w;
      }
    }
  }

  // ---- 4-way merge: m/l first (colbuf rows 0-1), then acc columns ----
  {
    float* redm = colbuf;          // [256]
    float* redl = colbuf + 256;    // [256]
    redm[tid] = mx; redl[tid] = l;
  }
  __syncthreads();                                    // B1
  float a0c, a1c, a2c, a3c, linv;
  {
    float m1 = colbuf[p1], m2 = colbuf[p2], m3 = colbuf[p3];
    float l1 = colbuf[256 + p1], l2 = colbuf[256 + p2], l3 = colbuf[256 + p3];
    float nm = fmaxf(fmaxf(mx, m1), fmaxf(m2, m3));
    a0c = __expf(mx - nm); a1c = __expf(m1 - nm);
    a2c = __expf(m2 - nm); a3c = __expf(m3 - nm);
    float L = l * a0c + l1 * a1c + l2 * a2c + l3 * a3c;
    linv = 1.f / L;
  }
  __syncthreads();                                    // B2 (m/l region free)
#pragma unroll
  for (int d = 0; d < 40; ++d) colbuf[d * 256 + tid] = acc[d];
  __syncthreads();                                    // B3
  float lat[40];
#pragma unroll
  for (int d = 0; d < 40; ++d)
    lat[d] = (acc[d] * a0c + colbuf[d * 256 + p1] * a1c
            + colbuf[d * 256 + p2] * a2c + colbuf[d * 256 + p3] * a3c) * linv;
  __syncthreads();                                    // B4 (colbuf free)

  // ---- lat2 = lat @ ca_out_w^T + ob, d-range split by wave (10 each) ----
  float lath[10];
#pragma unroll
  for (int dd = 0; dd < 10; ++dd) {
    float v = lat[dd];
    v = (h == 1) ? lat[dd + 10] : v;
    v = (h == 2) ? lat[dd + 20] : v;
    v = (h == 3) ? lat[dd + 30] : v;
    lath[dd] = v;
  }
  float lp[40];
#pragma unroll
  for (int e = 0; e < 40; ++e) lp[e] = 0.f;
#pragma unroll 1
  for (int dd = 0; dd < 10; ++dd) {
    const float lv = lath[dd];
    const int d = h * 10 + dd;
#pragma unroll
    for (int e = 0; e < 40; ++e) lp[e] += lv * ow[e * 40 + d];
  }
#pragma unroll
  for (int e = 0; e < 40; ++e) colbuf[e * 256 + tid] = lp[e];
  __syncthreads();                                    // B5
  float lat2[40];
#pragma unroll
  for (int e = 0; e < 40; ++e)
    lat2[e] = ob[e] + lp[e] + colbuf[e * 256 + p1]
            + colbuf[e * 256 + p2] + colbuf[e * 256 + p3];
  __syncthreads();                                    // B6 (colbuf free)

  // ---- LN + FFN (e-range split by wave: 40 each) ----
  float hh[40];
  {
    float m = 0.f;
#pragma unroll
    for (int d = 0; d < 40; ++d) m += lat2[d];
    m *= (1.f / 40.f);
    float var = 0.f;
#pragma unroll
    for (int d = 0; d < 40; ++d) { float dv = lat2[d] - m; var += dv * dv; }
    float rstd = rsqrtf(var * (1.f / 40.f) + 1e-5f);
#pragma unroll
    for (int d = 0; d < 40; ++d) hh[d] = (lat2[d] - m) * rstd * flw[d] + flb[d];
  }
  float ff[40];
#pragma unroll
  for (int d = 0; d < 40; ++d) ff[d] = 0.f;
#pragma unroll 1
  for (int ee = 0; ee < 40; ++ee) {
    const int e = h * 40 + ee;
    const float* r1 = w1 + e * 40;
    const float* r2 = w1 + (160 + e) * 40;
    float s0 = 0.f, s1 = 0.f;
#pragma unroll
    for (int d = 0; d < 40; ++d) { s0 += hh[d] * r1[d]; s1 += hh[d] * r2[d]; }
    float x1 = s0 + b1[e];
    float g = s1 + b1[160 + e];
    float tv = x1 * (0.5f * g * (1.f + erff(g * 0.70710678118654752f)));
#pragma unroll
    for (int d = 0; d < 40; ++d) ff[d] += tv * w2[d * 160 + e];
  }
#pragma unroll
  for (int d = 0; d < 40; ++d) colbuf[d * 256 + tid] = ff[d];
  __syncthreads();                                    // B7
  float r = outb[0];
#pragma unroll
  for (int d = 0; d < 40; ++d) {
    float f = ff[d] + colbuf[d * 256 + p1] + colbuf[d * 256 + p2]
            + colbuf[d * 256 + p3] + b2[d];
    r += (lat2[d] + f) * outw[d];
  }
  if (h == 0) out[n] = r;
}

// ---- fallback query (R8, PE inside) for small ws ----
__global__ __launch_bounds__(256) void query_kernel_fb(
    const float* __restrict__ qry,
    const float* __restrict__ pe_w, const float* __restrict__ pe_b,
    const float* __restrict__ lnq_w, const float* __restrict__ lnq_b,
    const float* __restrict__ qw,
    const float* __restrict__ ow, const float* __restrict__ ob,
    const float* __restrict__ flw, const float* __restrict__ flb,
    const float* __restrict__ w1, const float* __restrict__ b1,
    const float* __restrict__ w2, const float* __restrict__ b2,
    const float* __restrict__ outw, const float* __restrict__ outb,
    const float* __restrict__ kbuf, const float* __restrict__ vbuf,
    float* __restrict__ out)
{
  const int tid = threadIdx.x;
  const int h = __builtin_amdgcn_readfirstlane((tid >> 6) & 1);
  const int pj = tid >> 7;
  const int lane = tid & 63;
  const int n = blockIdx.x * 128 + pj * 64 + lane;
  const int ptn = tid ^ 64;
  __shared__ float colbuf[40 * 256];
  __shared__ float redm[256], redl[256];

  const float qx = qry[n * 3 + 0], qy = qry[n * 3 + 1], qz = qry[n * 3 + 2];
  float qp[40];
#pragma unroll
  for (int d = 0; d < 40; ++d) qp[d] = 0.f;
#pragma unroll
  for (int jj = 0; jj < 4; ++jj) {
    const int j = h * 4 + jj;
    float f = 3.14159265358979323846f * (float)(1 << j);
    float sx, cx, sy, cy, sz, cz;
    __sincosf(qx * f, &sx, &cx);
    __sincosf(qy * f, &sy, &cy);
    __sincosf(qz * f, &sz, &cz);
#pragma unroll
    for (int d = 0; d < 40; ++d) {
      const float* r = pe_w + d * 51;
      qp[d] += sx * r[j] + sy * r[j + 8] + sz * r[j + 16]
             + cx * r[j + 24] + cy * r[j + 32] + cz * r[j + 40];
    }
  }
#pragma unroll
  for (int d = 0; d < 40; ++d) colbuf[d * 256 + tid] = qp[d];
  __syncthreads();
  float qe[40];
#pragma unroll
  for (int d = 0; d < 40; ++d) {
    const float* r = pe_w + d * 51;
    qe[d] = pe_b[d] + qp[d] + colbuf[d * 256 + ptn]
          + qx * r[48] + qy * r[49] + qz * r[50];
  }
  __syncthreads();
  float qn[40];
  {
    float m = 0.f;
#pragma unroll
    for (int d = 0; d < 40; ++d) m += qe[d];
    m *= (1.f / 40.f);
    float var = 0.f;
#pragma unroll
    for (int d = 0; d < 40; ++d) { float dv = qe[d] - m; var += dv * dv; }
    float rstd = rsqrtf(var * (1.f / 40.f) + 1e-5f);
#pragma unroll
    for (int d = 0; d < 40; ++d) qn[d] = (qe[d] - m) * rstd * lnq_w[d] + lnq_b[d];
  }
  float qnh[20];
#pragma unroll
  for (int dd = 0; dd < 20; ++dd) qnh[dd] = h ? qn[dd + 20] : qn[dd];
  float q[40];
#pragma unroll
  for (int e = 0; e < 40; ++e) q[e] = 0.f;
#pragma unroll 1
  for (int dd = 0; dd < 20; ++dd) {
    const float qv = qnh[dd];
    const int d = h * 20 + dd;
#pragma unroll
    for (int e = 0; e < 40; ++e) q[e] += qv * qw[e * 40 + d];
  }
#pragma unroll
  for (int e = 0; e < 40; ++e) colbuf[e * 256 + tid] = q[e];
  __syncthreads();
#pragma unroll
  for (int e = 0; e < 40; ++e) q[e] += colbuf[e * 256 + ptn];
  __syncthreads();

  float acc[40];
#pragma unroll
  for (int d = 0; d < 40; ++d) acc[d] = 0.f;
  float mx = -1e30f, l = 0.f;
  const float scale = 0.15811388300841897f;
  const int tbeg = h * 200, tend = tbeg + 200;
#pragma unroll 1
  for (int t = tbeg; t < tend; ++t) {
    const float4* kr = (const float4*)(kbuf + t * 40);
    float s0 = 0.f, s1 = 0.f, s2 = 0.f, s3 = 0.f;
#pragma unroll
    for (int k = 0; k < 10; ++k) {
      float4 k4 = kr[k];
      s0 += q[4 * k] * k4.x; s1 += q[4 * k + 1] * k4.y;
      s2 += q[4 * k + 2] * k4.z; s3 += q[4 * k + 3] * k4.w;
    }
    float s = ((s0 + s1) + (s2 + s3)) * scale;
    if (s > mx) {
      float corr = __expf(mx - s);
      l *= corr;
#pragma unroll
      for (int d = 0; d < 40; ++d) acc[d] *= corr;
      mx = s;
    }
    float p = __expf(s - mx);
    l += p;
    const float4* vr = (const float4*)(vbuf + t * 40);
#pragma unroll
    for (int k = 0; k < 10; ++k) {
      float4 v4 = vr[k];
      acc[4 * k] += p * v4.x; acc[4 * k + 1] += p * v4.y;
      acc[4 * k + 2] += p * v4.z; acc[4 * k + 3] += p * v4.w;
    }
  }
#pragma unroll
  for (int d = 0; d < 40; ++d) colbuf[d * 256 + tid] = acc[d];
  redm[tid] = mx; redl[tid] = l;
  __syncthreads();
  float lat[40];
  {
    float m2 = redm[ptn];
    float l2 = redl[ptn];
    float nm = fmaxf(mx, m2);
    float a = __expf(mx - nm), b = __expf(m2 - nm);
    float lm = l * a + l2 * b;
    float linv = 1.f / lm;
#pragma unroll
    for (int d = 0; d < 40; ++d)
      lat[d] = (acc[d] * a + colbuf[d * 256 + ptn] * b) * linv;
  }
  __syncthreads();
  float lath[20];
#pragma unroll
  for (int dd = 0; dd < 20; ++dd) lath[dd] = h ? lat[dd + 20] : lat[dd];
  float lp[40];
#pragma unroll
  for (int e = 0; e < 40; ++e) lp[e] = 0.f;
#pragma unroll 1
  for (int dd = 0; dd < 20; ++dd) {
    const float lv = lath[dd];
    const int d = h * 20 + dd;
#pragma unroll
    for (int e = 0; e < 40; ++e) lp[e] += lv * ow[e * 40 + d];
  }
#pragma unroll
  for (int e = 0; e < 40; ++e) colbuf[e * 256 + tid] = lp[e];
  __syncthreads();
  float lat2[40];
#pragma unroll
  for (int e = 0; e < 40; ++e) lat2[e] = ob[e] + lp[e] + colbuf[e * 256 + ptn];
  __syncthreads();
  float hh[40];
  {
    float m = 0.f;
#pragma unroll
    for (int d = 0; d < 40; ++d) m += lat2[d];
    m *= (1.f / 40.f);
    float var = 0.f;
#pragma unroll
    for (int d = 0; d < 40; ++d) { float dv = lat2[d] - m; var += dv * dv; }
    float rstd = rsqrtf(var * (1.f / 40.f) + 1e-5f);
#pragma unroll
    for (int d = 0; d < 40; ++d) hh[d] = (lat2[d] - m) * rstd * flw[d] + flb[d];
  }
  float ff[40];
#pragma unroll
  for (int d = 0; d < 40; ++d) ff[d] = 0.f;
#pragma unroll 1
  for (int ee = 0; ee < 80; ++ee) {
    const int e = h * 80 + ee;
    const float* r1 = w1 + e * 40;
    const float* r2 = w1 + (160 + e) * 40;
    float s0 = 0.f, s1 = 0.f;
#pragma unroll
    for (int d = 0; d < 40; ++d) { s0 += hh[d] * r1[d]; s1 += hh[d] * r2[d]; }
    float x1 = s0 + b1[e];
    float g = s1 + b1[160 + e];
    float tv = x1 * (0.5f * g * (1.f + erff(g * 0.70710678118654752f)));
#pragma unroll
    for (int d = 0; d < 40; ++d) ff[d] += tv * w2[d * 160 + e];
  }
#pragma unroll
  for (int d = 0; d < 40; ++d) colbuf[d * 256 + tid] = ff[d];
  __syncthreads();
  float r = outb[0];
#pragma unroll
  for (int d = 0; d < 40; ++d) {
    float f = ff[d] + colbuf[d * 256 + ptn] + b2[d];
    r += (lat2[d] + f) * outw[d];
  }
  if (h == 0) out[n] = r;
}

extern "C" void kernel_launch(void* const* d_in, const int* in_sizes, int n_in,
                              void* d_out, int out_size, void* d_ws, size_t ws_size,
                              hipStream_t stream) {
  const float* mash   = (const float*)d_in[0];
  const float* qry    = (const float*)d_in[1];
  const float* lnw    = (const float*)d_in[2];
  const float* linw   = (const float*)d_in[3];
  const float* lconvw = (const float*)d_in[4];
  const float* lconvb = (const float*)d_in[5];
  const float* lxpw   = (const float*)d_in[6];
  const float* ldtw   = (const float*)d_in[7];
  const float* ldtb   = (const float*)d_in[8];
  const float* lAlog  = (const float*)d_in[9];
  const float* lD     = (const float*)d_in[10];
  const float* loutw  = (const float*)d_in[11];
  const float* pew    = (const float*)d_in[12];
  const float* peb    = (const float*)d_in[13];
  const float* lnqw   = (const float*)d_in[14];
  const float* lnqb   = (const float*)d_in[15];
  const float* lncw   = (const float*)d_in[16];
  const float* lncb   = (const float*)d_in[17];
  const float* qw     = (const float*)d_in[18];
  const float* kvw    = (const float*)d_in[19];
  const float* oww    = (const float*)d_in[20];
  const float* owb    = (const float*)d_in[21];
  const float* flnw   = (const float*)d_in[22];
  const float* flnb   = (const float*)d_in[23];
  const float* w1     = (const float*)d_in[24];
  const float* b1     = (const float*)d_in[25];
  const float* w2     = (const float*)d_in[26];
  const float* b2     = (const float*)d_in[27];
  const float* outw   = (const float*)d_in[28];
  const float* outb   = (const float*)d_in[29];

  // ws layout (floats): xb0[16000] xb1[16000] k[16000] v[16000]
  //                     flags[4096 ints] qstore[40*65536]
  float* wsf = (float*)d_ws;
  float* xb0 = wsf;
  float* xb1 = wsf + 16000;
  float* kbuf = wsf + 32000;
  float* vbuf = wsf + 48000;
  int* flags = (int*)(wsf + 64000);
  float* qstore = wsf + 68096;
  const size_t needed = (size_t)68096 * 4 + (size_t)40 * 65536 * 4;
  const bool pre = ws_size >= needed;   // constant across calls -> capture-safe

  hipLaunchKernelGGL(init_flags, dim3(16), dim3(256), 0, stream, flags);
  // 256 layer blocks + (pre ? 205 PE blocks : 0); layer blocks dispatch first
  hipLaunchKernelGGL(mamba_pipe, dim3(pre ? 461 : 256), dim3(TPB1), 0, stream,
                     mash, lnw, linw, lconvw, lconvb, lxpw, ldtw, ldtb, lAlog,
                     lD, loutw, xb0, xb1, flags,
                     qry, pew, peb, lnqw, lnqb, qw, qstore);
  // layer 255 (odd) writes xb1
  hipLaunchKernelGGL(kv_kernel, dim3(400), dim3(64), 0, stream,
                     xb1, lncw, lncb, kvw, kbuf, vbuf);
  if (pre) {
    hipLaunchKernelGGL(query_fast, dim3(1024), dim3(256), 0, stream,
                       qstore, oww, owb, flnw, flnb,
                       w1, b1, w2, b2, outw, outb, kbuf, vbuf, (float*)d_out);
  } else {
    hipLaunchKernelGGL(query_kernel_fb, dim3(512), dim3(256), 0, stream,
                       qry, pew, peb, lnqw, lnqb, qw, oww, owb, flnw, flnb,
                       w1, b1, w2, b2, outw, outb, kbuf, vbuf, (float*)d_out);
  }
}